// Round 1
// baseline (429.752 us; speedup 1.0000x reference)
//
#include <hip/hip_runtime.h>

typedef unsigned short u16;
typedef short s16x8 __attribute__((ext_vector_type(8)));
typedef float f32x4 __attribute__((ext_vector_type(4)));

// ---------- bf16 helpers (bit-level, no hip_bf16 dependency) ----------
__device__ __forceinline__ u16 f2bf(float f) {
    union { float f; unsigned u; } v; v.f = f;
    unsigned r = v.u + 0x7FFFu + ((v.u >> 16) & 1u);   // round-to-nearest-even
    return (u16)(r >> 16);
}
__device__ __forceinline__ float bf2f(u16 h) {
    union { unsigned u; float f; } v; v.u = ((unsigned)h) << 16;
    return v.f;
}

// ---------- fp32 -> bf16 convert (vectorized) ----------
__global__ __launch_bounds__(256) void f32_to_bf16(const float* __restrict__ in,
                                                   u16* __restrict__ out, int n) {
    int i = (blockIdx.x * 256 + threadIdx.x) * 4;
    int stride = gridDim.x * 256 * 4;
    for (; i < n; i += stride) {
        float4 v = *reinterpret_cast<const float4*>(in + i);
        ushort4 o;
        o.x = f2bf(v.x); o.y = f2bf(v.y); o.z = f2bf(v.z); o.w = f2bf(v.w);
        *reinterpret_cast<ushort4*>(out + i) = o;
    }
}

// ---------- bf16 GEMM, C = A @ B^T.  A:[M,K] lda, B:[N,K] ldb, C:[M,N] ldc ----------
// MODE 0: plain.  MODE 1: causal tile skip (bx>by upper-tri blocks untouched).
// MODE 2: per-row-tile K limit (PV with P zero above diagonal): kend=min(K,(by+1)*128).
#define BM 128
#define BN 128
#define BKK 32

template <int MODE, typename CT>
__global__ __launch_bounds__(256)
void gemm_bt(const u16* __restrict__ A, const u16* __restrict__ B, CT* __restrict__ C,
             int M, int N, int K, int lda, int ldb, int ldc) {
    const int bx = blockIdx.x;   // N tile
    const int by = blockIdx.y;   // M tile
    if (MODE == 1 && bx > by) return;
    int kend = K;
    if (MODE == 2) { int kl = (by + 1) * BM; kend = kl < K ? kl : K; }

    __shared__ u16 Asm[BM * BKK];
    __shared__ u16 Bsm[BN * BKK];

    const int tid  = threadIdx.x;
    const int lane = tid & 63;
    const int wave = tid >> 6;
    const int wr = (wave >> 1) * 64;   // wave row offset
    const int wc = (wave & 1) * 64;    // wave col offset
    const int fr = lane & 15;          // fragment row/col within 16
    const int fq = lane >> 4;          // k-chunk 0..3

    const int tm = by * BM, tn = bx * BN;

    f32x4 acc[4][4];
#pragma unroll
    for (int m = 0; m < 4; ++m)
#pragma unroll
        for (int n = 0; n < 4; ++n) acc[m][n] = {0.f, 0.f, 0.f, 0.f};

    for (int k0 = 0; k0 < kend; k0 += BKK) {
        // stage A,B tiles: 512 groups of 8 bf16 each; thread does groups tid, tid+256
#pragma unroll
        for (int r = 0; r < 2; ++r) {
            int idx = r * 256 + tid;
            int row = idx >> 2;
            int col = (idx & 3) * 8;
            uint4 va = *reinterpret_cast<const uint4*>(A + (size_t)(tm + row) * lda + k0 + col);
            *reinterpret_cast<uint4*>(&Asm[row * BKK + col]) = va;
            uint4 vb = *reinterpret_cast<const uint4*>(B + (size_t)(tn + row) * ldb + k0 + col);
            *reinterpret_cast<uint4*>(&Bsm[row * BKK + col]) = vb;
        }
        __syncthreads();

        s16x8 af[4], bfr[4];
#pragma unroll
        for (int m = 0; m < 4; ++m)
            af[m] = *reinterpret_cast<const s16x8*>(&Asm[(wr + m * 16 + fr) * BKK + fq * 8]);
#pragma unroll
        for (int n = 0; n < 4; ++n)
            bfr[n] = *reinterpret_cast<const s16x8*>(&Bsm[(wc + n * 16 + fr) * BKK + fq * 8]);
#pragma unroll
        for (int m = 0; m < 4; ++m)
#pragma unroll
            for (int n = 0; n < 4; ++n)
                acc[m][n] = __builtin_amdgcn_mfma_f32_16x16x32_bf16(af[m], bfr[n], acc[m][n], 0, 0, 0);
        __syncthreads();
    }

    // epilogue: D row=(lane>>4)*4+r, col=lane&15  (m89-verified mapping)
#pragma unroll
    for (int m = 0; m < 4; ++m)
#pragma unroll
        for (int n = 0; n < 4; ++n)
#pragma unroll
            for (int r = 0; r < 4; ++r) {
                int row = tm + wr + m * 16 + fq * 4 + r;
                int col = tn + wc + n * 16 + fr;
                float v = acc[m][n][r];
                if constexpr (sizeof(CT) == 2) C[(size_t)row * ldc + col] = f2bf(v);
                else                           C[(size_t)row * ldc + col] = v;
            }
}

// ---------- RoPE (full d=1024, half-rotate) + L2 norm * sqk*32, in-place on Q,K ----------
__global__ __launch_bounds__(256)
void rope_norm(u16* __restrict__ qkv, const float* __restrict__ sqk) {
    const int row = blockIdx.x;        // b*2048 + t
    const int t = row & 2047;
    u16* qp = qkv + (size_t)row * 3072;
    u16* kp = qp + 1024;

    const float L = 0.025952563241307517f;  // log2(10000)/512
    float q0v[2], q1v[2], k0v[2], k1v[2];
    float ssq_q = 0.f, ssq_k = 0.f;

#pragma unroll
    for (int i = 0; i < 2; ++i) {
        int d = threadIdx.x + i * 256;           // 0..511
        float invf = exp2f(-(float)d * L);
        float ang = (float)t * invf;
        float s, c;
        sincosf(ang, &s, &c);
        float q0 = bf2f(qp[d]), q1 = bf2f(qp[d + 512]);
        float k0 = bf2f(kp[d]), k1 = bf2f(kp[d + 512]);
        float nq0 = q0 * c - q1 * s;
        float nq1 = q1 * c + q0 * s;
        float nk0 = k0 * c - k1 * s;
        float nk1 = k1 * c + k0 * s;
        q0v[i] = nq0; q1v[i] = nq1; k0v[i] = nk0; k1v[i] = nk1;
        ssq_q += nq0 * nq0 + nq1 * nq1;
        ssq_k += nk0 * nk0 + nk1 * nk1;
    }

    // block reduce both sums
#pragma unroll
    for (int off = 32; off; off >>= 1) {
        ssq_q += __shfl_xor(ssq_q, off);
        ssq_k += __shfl_xor(ssq_k, off);
    }
    __shared__ float red[8];
    int wave = threadIdx.x >> 6, lane = threadIdx.x & 63;
    if (lane == 0) { red[wave] = ssq_q; red[4 + wave] = ssq_k; }
    __syncthreads();
    float rq = rsqrtf(red[0] + red[1] + red[2] + red[3]);
    float rk = rsqrtf(red[4] + red[5] + red[6] + red[7]);

#pragma unroll
    for (int i = 0; i < 2; ++i) {
        int d = threadIdx.x + i * 256;
        float s0 = sqk[d] * 32.f, s1 = sqk[d + 512] * 32.f;
        qp[d]       = f2bf(q0v[i] * rq * s0);
        qp[d + 512] = f2bf(q1v[i] * rq * s1);
        kp[d]       = f2bf(k0v[i] * rk * s0);
        kp[d + 512] = f2bf(k1v[i] * rk * s1);
    }
}

// ---------- V transpose: VT[b][n][k] = qkv[(b*2048+k)][2048+n] ----------
__global__ __launch_bounds__(256)
void transpose_v(const u16* __restrict__ qkv, u16* __restrict__ VT) {
    __shared__ u16 tile[32][33];
    int b = blockIdx.z;
    int n0 = blockIdx.x * 32;
    int k0 = blockIdx.y * 32;
    int tx = threadIdx.x, ty = threadIdx.y;
    const u16* src = qkv + (size_t)b * 2048 * 3072 + 2048;
#pragma unroll
    for (int i = 0; i < 4; ++i)
        tile[ty + i * 8][tx] = src[(size_t)(k0 + ty + i * 8) * 3072 + n0 + tx];
    __syncthreads();
    u16* dst = VT + (size_t)b * 1024 * 2048;
#pragma unroll
    for (int i = 0; i < 4; ++i)
        dst[(size_t)(n0 + ty + i * 8) * 2048 + k0 + tx] = tile[tx][ty + i * 8];
}

// ---------- causal row softmax: P = softmax(32*S[r, 0..r]), zeros for c>r ----------
__global__ __launch_bounds__(256)
void softmax_row(const float* __restrict__ S, u16* __restrict__ P) {
    const int T = 2048;
    int r = blockIdx.x;
    const float* srow = S + (size_t)r * T;
    u16* prow = P + (size_t)r * T;
    int n = r + 1;
    int tid = threadIdx.x;

    float m = -1e30f;
    for (int c = tid; c < n; c += 256) m = fmaxf(m, srow[c]);
#pragma unroll
    for (int off = 32; off; off >>= 1) m = fmaxf(m, __shfl_xor(m, off));
    __shared__ float redm[4], redsum[4];
    int wave = tid >> 6, lane = tid & 63;
    if (lane == 0) redm[wave] = m;
    __syncthreads();
    m = fmaxf(fmaxf(redm[0], redm[1]), fmaxf(redm[2], redm[3]));
    float M = 32.f * m;

    float sum = 0.f;
    for (int c = tid; c < n; c += 256) sum += __expf(32.f * srow[c] - M);
#pragma unroll
    for (int off = 32; off; off >>= 1) sum += __shfl_xor(sum, off);
    if (lane == 0) redsum[wave] = sum;
    __syncthreads();
    sum = redsum[0] + redsum[1] + redsum[2] + redsum[3];
    float inv = 1.f / sum;

    for (int c = tid; c < T; c += 256) {
        float p = (c < n) ? __expf(32.f * srow[c] - M) * inv : 0.f;
        prow[c] = f2bf(p);
    }
}

// ---------- host launcher ----------
extern "C" void kernel_launch(void* const* d_in, const int* in_sizes, int n_in,
                              void* d_out, int out_size, void* d_ws, size_t ws_size,
                              hipStream_t stream) {
    const float* x   = (const float*)d_in[0];   // [4,2048,1024]
    const float* w   = (const float*)d_in[1];   // [3072,1024]
    const float* sqk = (const float*)d_in[2];   // [1024]
    float* out = (float*)d_out;

    // workspace layout (needs ~110 MB)
    const size_t SZ_XB  = (size_t)8192 * 1024 * 2;
    const size_t SZ_WB  = (size_t)3072 * 1024 * 2;
    const size_t SZ_QKV = (size_t)8192 * 3072 * 2;
    const size_t SZ_VT  = (size_t)4 * 1024 * 2048 * 2;
    const size_t SZ_S   = (size_t)2048 * 2048 * 4;
    const size_t SZ_P   = (size_t)2048 * 2048 * 2;
    if (ws_size < SZ_XB + SZ_WB + SZ_QKV + SZ_VT + SZ_S + SZ_P) return;  // sentinel: output stays zero

    char* ws = (char*)d_ws;
    u16*   xb  = (u16*)ws;  ws += SZ_XB;
    u16*   wb  = (u16*)ws;  ws += SZ_WB;
    u16*   qkv = (u16*)ws;  ws += SZ_QKV;
    u16*   VT  = (u16*)ws;  ws += SZ_VT;
    float* S   = (float*)ws; ws += SZ_S;
    u16*   P   = (u16*)ws;  ws += SZ_P;

    f32_to_bf16<<<2048, 256, 0, stream>>>(x, xb, 8192 * 1024);
    f32_to_bf16<<<768, 256, 0, stream>>>(w, wb, 3072 * 1024);

    // qkv = x @ W^T : [8192,3072]
    gemm_bt<0, u16><<<dim3(3072 / BN, 8192 / BM), 256, 0, stream>>>(
        xb, wb, qkv, 8192, 3072, 1024, 1024, 1024, 3072);

    rope_norm<<<8192, 256, 0, stream>>>(qkv, sqk);

    transpose_v<<<dim3(32, 64, 4), dim3(32, 8), 0, stream>>>(qkv, VT);

    for (int b = 0; b < 4; ++b) {
        const u16* Qb = qkv + (size_t)b * 2048 * 3072;
        const u16* Kb = Qb + 1024;
        const u16* Vb = VT + (size_t)b * 1024 * 2048;
        // S = Q @ K^T (causal tiles only)
        gemm_bt<1, float><<<dim3(16, 16), 256, 0, stream>>>(
            Qb, Kb, S, 2048, 2048, 1024, 3072, 3072, 2048);
        softmax_row<<<2048, 256, 0, stream>>>(S, P);
        // out_b = P @ V  (B = VT_b is [1024][2048] = V^T, row-major)
        gemm_bt<2, float><<<dim3(1024 / BN, 16), 256, 0, stream>>>(
            P, Vb, out + (size_t)b * 2048 * 1024, 2048, 1024, 2048, 2048, 2048, 1024);
    }
}

// Round 2
// 279.175 us; speedup vs baseline: 1.5394x; 1.5394x over previous
//
#include <hip/hip_runtime.h>

typedef unsigned short u16;
typedef short s16x8 __attribute__((ext_vector_type(8)));
typedef float f32x4 __attribute__((ext_vector_type(4)));

// ---------- bf16 helpers ----------
__device__ __forceinline__ u16 f2bf(float f) {
    union { float f; unsigned u; } v; v.f = f;
    unsigned r = v.u + 0x7FFFu + ((v.u >> 16) & 1u);   // RNE
    return (u16)(r >> 16);
}
__device__ __forceinline__ float bf2f(u16 h) {
    union { unsigned u; float f; } v; v.u = ((unsigned)h) << 16;
    return v.f;
}

// async global->LDS, 16B per lane; LDS dest = wave-uniform base + lane*16
__device__ __forceinline__ void gl_lds16(const u16* g, u16* l) {
    __builtin_amdgcn_global_load_lds(
        (const __attribute__((address_space(1))) void*)g,
        (__attribute__((address_space(3))) void*)l,
        16, 0, 0);
}

// ---------- fp32 -> bf16 convert ----------
__global__ __launch_bounds__(256) void f32_to_bf16(const float* __restrict__ in,
                                                   u16* __restrict__ out, int n) {
    int i = (blockIdx.x * 256 + threadIdx.x) * 4;
    int stride = gridDim.x * 256 * 4;
    for (; i < n; i += stride) {
        float4 v = *reinterpret_cast<const float4*>(in + i);
        ushort4 o;
        o.x = f2bf(v.x); o.y = f2bf(v.y); o.z = f2bf(v.z); o.w = f2bf(v.w);
        *reinterpret_cast<ushort4*>(out + i) = o;
    }
}

// ---------- bf16 GEMM, C = A @ B^T, m97-structure (global_load_lds staging) ----------
// MODE 0: plain. MODE 1: causal tile skip. MODE 2: per-row-tile K limit (PV).
// Batched over blockIdx.z with element strides sA,sB,sC.
#define BM 128
#define BN 128
#define BKK 32

template <int MODE, typename CT>
__global__ __launch_bounds__(256)
void gemm_bt(const u16* __restrict__ A, const u16* __restrict__ B, CT* __restrict__ C,
             int K, int lda, int ldb, int ldc, long sA, long sB, long sC) {
    const int bx = blockIdx.x, by = blockIdx.y, bz = blockIdx.z;
    if (MODE == 1 && bx > by) return;
    A += (size_t)bz * sA; B += (size_t)bz * sB; C += (size_t)bz * sC;
    int kend = K;
    if (MODE == 2) { int kl = (by + 1) * BM; kend = kl < K ? kl : K; }

    __shared__ u16 Asm[BM * BKK];
    __shared__ u16 Bsm[BN * BKK];

    const int tid  = threadIdx.x;
    const int lane = tid & 63;
    const int wave = tid >> 6;
    const int wr = (wave >> 1) * 64;
    const int wc = (wave & 1) * 64;
    const int fr = lane & 15;
    const int fq = lane >> 4;
    const int tm = by * BM, tn = bx * BN;

    // staging geometry: 8 chunks of 1024B per tile; wave w does chunks 2w, 2w+1
    const int c0 = wave * 2;
    const int i0 = c0 * 64 + lane, i1 = i0 + 64;
    const int r0 = i0 >> 2, col0 = (i0 & 3) * 8;
    const int r1 = i1 >> 2, col1 = (i1 & 3) * 8;
    const u16* ag0 = A + (size_t)(tm + r0) * lda + col0;
    const u16* ag1 = A + (size_t)(tm + r1) * lda + col1;
    const u16* bg0 = B + (size_t)(tn + r0) * ldb + col0;
    const u16* bg1 = B + (size_t)(tn + r1) * ldb + col1;
    u16* la0 = &Asm[c0 * 512];
    u16* la1 = &Asm[c0 * 512 + 512];
    u16* lb0 = &Bsm[c0 * 512];
    u16* lb1 = &Bsm[c0 * 512 + 512];

    f32x4 acc[4][4];
#pragma unroll
    for (int m = 0; m < 4; ++m)
#pragma unroll
        for (int n = 0; n < 4; ++n) acc[m][n] = {0.f, 0.f, 0.f, 0.f};

    for (int k0 = 0; k0 < kend; k0 += BKK) {
        gl_lds16(ag0 + k0, la0);
        gl_lds16(ag1 + k0, la1);
        gl_lds16(bg0 + k0, lb0);
        gl_lds16(bg1 + k0, lb1);
        __syncthreads();   // drains vmcnt before LDS reads

        s16x8 af[4], bfr[4];
#pragma unroll
        for (int m = 0; m < 4; ++m)
            af[m] = *reinterpret_cast<const s16x8*>(&Asm[(wr + m * 16 + fr) * BKK + fq * 8]);
#pragma unroll
        for (int n = 0; n < 4; ++n)
            bfr[n] = *reinterpret_cast<const s16x8*>(&Bsm[(wc + n * 16 + fr) * BKK + fq * 8]);
#pragma unroll
        for (int m = 0; m < 4; ++m)
#pragma unroll
            for (int n = 0; n < 4; ++n)
                acc[m][n] = __builtin_amdgcn_mfma_f32_16x16x32_bf16(af[m], bfr[n], acc[m][n], 0, 0, 0);
        __syncthreads();
    }

    // epilogue: D row=(lane>>4)*4+r, col=lane&15 (m89-verified)
#pragma unroll
    for (int m = 0; m < 4; ++m)
#pragma unroll
        for (int n = 0; n < 4; ++n)
#pragma unroll
            for (int r = 0; r < 4; ++r) {
                int row = tm + wr + m * 16 + fq * 4 + r;
                int col = tn + wc + n * 16 + fr;
                float v = acc[m][n][r];
                if constexpr (sizeof(CT) == 2) C[(size_t)row * ldc + col] = f2bf(v);
                else                           C[(size_t)row * ldc + col] = v;
            }
}

// ---------- RoPE + L2 norm * sqk*32, in-place on Q,K ----------
__global__ __launch_bounds__(256)
void rope_norm(u16* __restrict__ qkv, const float* __restrict__ sqk) {
    const int row = blockIdx.x;        // b*2048 + t
    const int t = row & 2047;
    u16* qp = qkv + (size_t)row * 3072;
    u16* kp = qp + 1024;

    const float L = 0.025952563241307517f;  // log2(10000)/512
    float q0v[2], q1v[2], k0v[2], k1v[2];
    float ssq_q = 0.f, ssq_k = 0.f;

#pragma unroll
    for (int i = 0; i < 2; ++i) {
        int d = threadIdx.x + i * 256;           // 0..511
        float invf = exp2f(-(float)d * L);
        float ang = (float)t * invf;
        float s, c;
        sincosf(ang, &s, &c);
        float q0 = bf2f(qp[d]), q1 = bf2f(qp[d + 512]);
        float k0 = bf2f(kp[d]), k1 = bf2f(kp[d + 512]);
        float nq0 = q0 * c - q1 * s;
        float nq1 = q1 * c + q0 * s;
        float nk0 = k0 * c - k1 * s;
        float nk1 = k1 * c + k0 * s;
        q0v[i] = nq0; q1v[i] = nq1; k0v[i] = nk0; k1v[i] = nk1;
        ssq_q += nq0 * nq0 + nq1 * nq1;
        ssq_k += nk0 * nk0 + nk1 * nk1;
    }

#pragma unroll
    for (int off = 32; off; off >>= 1) {
        ssq_q += __shfl_xor(ssq_q, off);
        ssq_k += __shfl_xor(ssq_k, off);
    }
    __shared__ float red[8];
    int wave = threadIdx.x >> 6, lane = threadIdx.x & 63;
    if (lane == 0) { red[wave] = ssq_q; red[4 + wave] = ssq_k; }
    __syncthreads();
    float rq = rsqrtf(red[0] + red[1] + red[2] + red[3]);
    float rk = rsqrtf(red[4] + red[5] + red[6] + red[7]);

#pragma unroll
    for (int i = 0; i < 2; ++i) {
        int d = threadIdx.x + i * 256;
        float s0 = sqk[d] * 32.f, s1 = sqk[d + 512] * 32.f;
        qp[d]       = f2bf(q0v[i] * rq * s0);
        qp[d + 512] = f2bf(q1v[i] * rq * s1);
        kp[d]       = f2bf(k0v[i] * rk * s0);
        kp[d + 512] = f2bf(k1v[i] * rk * s1);
    }
}

// ---------- V transpose: VT[b][n][k] = qkv[(b*2048+k)][2048+n] ----------
__global__ __launch_bounds__(256)
void transpose_v(const u16* __restrict__ qkv, u16* __restrict__ VT) {
    __shared__ u16 tile[32][33];
    int b = blockIdx.z;
    int n0 = blockIdx.x * 32;
    int k0 = blockIdx.y * 32;
    int tx = threadIdx.x, ty = threadIdx.y;
    const u16* src = qkv + (size_t)b * 2048 * 3072 + 2048;
#pragma unroll
    for (int i = 0; i < 4; ++i)
        tile[ty + i * 8][tx] = src[(size_t)(k0 + ty + i * 8) * 3072 + n0 + tx];
    __syncthreads();
    u16* dst = VT + (size_t)b * 1024 * 2048;
#pragma unroll
    for (int i = 0; i < 4; ++i)
        dst[(size_t)(n0 + ty + i * 8) * 2048 + k0 + tx] = tile[tx][ty + i * 8];
}

// ---------- in-place causal softmax: P(bf16) written into second half of each S row ----------
// S slot layout: [2048 rows][2048 fp32]; P row r = bytes [4096,8192) of row r, 2048 u16.
__global__ __launch_bounds__(256)
void softmax_inplace(float* __restrict__ S) {
    const int T = 2048;
    const int r = blockIdx.x;
    const int slot = blockIdx.y;
    float* srow = S + (size_t)slot * 4194304 + (size_t)r * T;
    u16* prow = (u16*)srow + 2048;
    const int n = r + 1;
    const int tid = threadIdx.x;

    float v[8];
    float m = -1e30f;
#pragma unroll
    for (int i = 0; i < 8; ++i) {
        int c = tid + i * 256;
        v[i] = (c < n) ? srow[c] : -1e30f;
        m = fmaxf(m, v[i]);
    }
#pragma unroll
    for (int off = 32; off; off >>= 1) m = fmaxf(m, __shfl_xor(m, off));
    __shared__ float redm[4], redsum[4];
    int wave = tid >> 6, lane = tid & 63;
    if (lane == 0) redm[wave] = m;
    __syncthreads();
    m = fmaxf(fmaxf(redm[0], redm[1]), fmaxf(redm[2], redm[3]));
    float M = 32.f * m;

    float sum = 0.f;
#pragma unroll
    for (int i = 0; i < 8; ++i) {
        int c = tid + i * 256;
        float e = (c < n) ? __expf(32.f * v[i] - M) : 0.f;
        v[i] = e;
        sum += e;
    }
#pragma unroll
    for (int off = 32; off; off >>= 1) sum += __shfl_xor(sum, off);
    if (lane == 0) redsum[wave] = sum;
    __syncthreads();   // also orders all srow reads before prow writes
    sum = redsum[0] + redsum[1] + redsum[2] + redsum[3];
    float inv = 1.f / sum;

#pragma unroll
    for (int i = 0; i < 8; ++i) {
        int c = tid + i * 256;
        prow[c] = f2bf(v[i] * inv);
    }
}

// ---------- host launcher ----------
extern "C" void kernel_launch(void* const* d_in, const int* in_sizes, int n_in,
                              void* d_out, int out_size, void* d_ws, size_t ws_size,
                              hipStream_t stream) {
    const float* x   = (const float*)d_in[0];   // [4,2048,1024]
    const float* w   = (const float*)d_in[1];   // [3072,1024]
    const float* sqk = (const float*)d_in[2];   // [1024]
    float* out = (float*)d_out;

    const size_t SZ_XB  = (size_t)8192 * 1024 * 2;   // also holds VT after QKV GEMM
    const size_t SZ_WB  = (size_t)3072 * 1024 * 2;
    const size_t SZ_QKV = (size_t)8192 * 3072 * 2;
    const size_t SZ_S   = (size_t)2 * 2048 * 2048 * 4;  // 2 batch slots
    if (ws_size < SZ_XB + SZ_WB + SZ_QKV + SZ_S) return;

    char* ws = (char*)d_ws;
    u16*   xb  = (u16*)ws;  ws += SZ_XB;
    u16*   wb  = (u16*)ws;  ws += SZ_WB;
    u16*   qkv = (u16*)ws;  ws += SZ_QKV;
    float* S   = (float*)ws;
    u16*   VT  = xb;   // alias: xb dead after QKV GEMM

    f32_to_bf16<<<2048, 256, 0, stream>>>(x, xb, 8192 * 1024);
    f32_to_bf16<<<768, 256, 0, stream>>>(w, wb, 3072 * 1024);

    // qkv = x @ W^T : [8192,3072]
    gemm_bt<0, u16><<<dim3(3072 / BN, 8192 / BM, 1), 256, 0, stream>>>(
        xb, wb, qkv, 1024, 1024, 1024, 3072, 0, 0, 0);

    rope_norm<<<8192, 256, 0, stream>>>(qkv, sqk);

    transpose_v<<<dim3(32, 64, 4), dim3(32, 8), 0, stream>>>(qkv, VT);

    for (int g = 0; g < 2; ++g) {
        const u16* Qb = qkv + (size_t)g * 2 * 2048 * 3072;
        const u16* Kb = Qb + 1024;
        // S = Q @ K^T (causal tiles, 2 batches per launch)
        gemm_bt<1, float><<<dim3(16, 16, 2), 256, 0, stream>>>(
            Qb, Kb, S, 1024, 3072, 3072, 2048,
            (long)2048 * 3072, (long)2048 * 3072, (long)2048 * 2048);
        softmax_inplace<<<dim3(2048, 2), 256, 0, stream>>>(S);
        // out = P @ V; P embedded in S rows (lda=4096 u16, base offset 2048 u16)
        gemm_bt<2, float><<<dim3(8, 16, 2), 256, 0, stream>>>(
            (const u16*)(void*)S + 2048, VT + (size_t)g * 2 * 1024 * 2048,
            out + (size_t)g * 2 * 2048 * 1024, 2048, 4096, 2048, 1024,
            (long)8388608, (long)1024 * 2048, (long)2048 * 1024);
    }
}

// Round 3
// 239.478 us; speedup vs baseline: 1.7945x; 1.1658x over previous
//
#include <hip/hip_runtime.h>

typedef unsigned short u16;
typedef short s16x8 __attribute__((ext_vector_type(8)));
typedef float f32x4 __attribute__((ext_vector_type(4)));

// ---------- scalar dtype helpers ----------
__device__ __forceinline__ u16 f2bf(float f) {
    union { float f; unsigned u; } v; v.f = f;
    unsigned r = v.u + 0x7FFFu + ((v.u >> 16) & 1u);   // RNE
    return (u16)(r >> 16);
}
__device__ __forceinline__ float bf2f(u16 h) {
    union { unsigned u; float f; } v; v.u = ((unsigned)h) << 16;
    return v.f;
}
__device__ __forceinline__ u16 f2h(float f) {
    _Float16 h = (_Float16)f;
    union { _Float16 h; u16 u; } v; v.h = h; return v.u;
}
__device__ __forceinline__ float h2f(u16 u) {
    union { u16 u; _Float16 h; } v; v.u = u; return (float)v.h;
}

// async global->LDS, 16B per lane; LDS dest = wave-uniform base + lane*16
__device__ __forceinline__ void gl_lds16(const u16* g, u16* l) {
    __builtin_amdgcn_global_load_lds(
        (const __attribute__((address_space(1))) void*)g,
        (__attribute__((address_space(3))) void*)l,
        16, 0, 0);
}

// ---------- fp32 -> bf16 convert ----------
__global__ __launch_bounds__(256) void f32_to_bf16(const float* __restrict__ in,
                                                   u16* __restrict__ out, int n) {
    int i = (blockIdx.x * 256 + threadIdx.x) * 4;
    int stride = gridDim.x * 256 * 4;
    for (; i < n; i += stride) {
        float4 v = *reinterpret_cast<const float4*>(in + i);
        ushort4 o;
        o.x = f2bf(v.x); o.y = f2bf(v.y); o.z = f2bf(v.z); o.w = f2bf(v.w);
        *reinterpret_cast<ushort4*>(out + i) = o;
    }
}

// ---------- C store dispatch: u16 -> bf16, _Float16 -> fp16, float -> f32 ----------
template <typename CT>
__device__ __forceinline__ void store_c(CT* p, float v) {
    if constexpr (__is_same(CT, u16))            *p = f2bf(v);
    else if constexpr (__is_same(CT, _Float16))  *p = (_Float16)v;
    else                                         *p = v;
}

// ---------- bf16 GEMM, C = A @ B^T (m97-structure) ----------
// MODE 0: plain. MODE 1: causal tile skip. MODE 2: per-row-tile K limit (PV).
#define BM 128
#define BN 128
#define BKK 32

template <int MODE, typename CT>
__global__ __launch_bounds__(256)
void gemm_bt(const u16* __restrict__ A, const u16* __restrict__ B, CT* __restrict__ C,
             int K, int lda, int ldb, int ldc, long sA, long sB, long sC) {
    const int bx = blockIdx.x, by = blockIdx.y, bz = blockIdx.z;
    if (MODE == 1 && bx > by) return;
    A += (size_t)bz * sA; B += (size_t)bz * sB; C += (size_t)bz * sC;
    int kend = K;
    if (MODE == 2) { int kl = (by + 1) * BM; kend = kl < K ? kl : K; }

    __shared__ u16 Asm[BM * BKK];
    __shared__ u16 Bsm[BN * BKK];

    const int tid  = threadIdx.x;
    const int lane = tid & 63;
    const int wave = tid >> 6;
    const int wr = (wave >> 1) * 64;
    const int wc = (wave & 1) * 64;
    const int fr = lane & 15;
    const int fq = lane >> 4;
    const int tm = by * BM, tn = bx * BN;

    // staging: 8 chunks of 1024B per tile; wave w does chunks 2w, 2w+1
    const int c0 = wave * 2;
    const int i0 = c0 * 64 + lane, i1 = i0 + 64;
    const int r0 = i0 >> 2, col0 = (i0 & 3) * 8;
    const int r1 = i1 >> 2, col1 = (i1 & 3) * 8;
    const u16* ag0 = A + (size_t)(tm + r0) * lda + col0;
    const u16* ag1 = A + (size_t)(tm + r1) * lda + col1;
    const u16* bg0 = B + (size_t)(tn + r0) * ldb + col0;
    const u16* bg1 = B + (size_t)(tn + r1) * ldb + col1;
    u16* la0 = &Asm[c0 * 512];
    u16* la1 = &Asm[c0 * 512 + 512];
    u16* lb0 = &Bsm[c0 * 512];
    u16* lb1 = &Bsm[c0 * 512 + 512];

    f32x4 acc[4][4];
#pragma unroll
    for (int m = 0; m < 4; ++m)
#pragma unroll
        for (int n = 0; n < 4; ++n) acc[m][n] = {0.f, 0.f, 0.f, 0.f};

    for (int k0 = 0; k0 < kend; k0 += BKK) {
        gl_lds16(ag0 + k0, la0);
        gl_lds16(ag1 + k0, la1);
        gl_lds16(bg0 + k0, lb0);
        gl_lds16(bg1 + k0, lb1);
        __syncthreads();

        s16x8 af[4], bfr[4];
#pragma unroll
        for (int m = 0; m < 4; ++m)
            af[m] = *reinterpret_cast<const s16x8*>(&Asm[(wr + m * 16 + fr) * BKK + fq * 8]);
#pragma unroll
        for (int n = 0; n < 4; ++n)
            bfr[n] = *reinterpret_cast<const s16x8*>(&Bsm[(wc + n * 16 + fr) * BKK + fq * 8]);
#pragma unroll
        for (int m = 0; m < 4; ++m)
#pragma unroll
            for (int n = 0; n < 4; ++n)
                acc[m][n] = __builtin_amdgcn_mfma_f32_16x16x32_bf16(af[m], bfr[n], acc[m][n], 0, 0, 0);
        __syncthreads();
    }

    // epilogue: D row=(lane>>4)*4+r, col=lane&15 (m89-verified)
#pragma unroll
    for (int m = 0; m < 4; ++m)
#pragma unroll
        for (int n = 0; n < 4; ++n)
#pragma unroll
            for (int r = 0; r < 4; ++r) {
                int row = tm + wr + m * 16 + fq * 4 + r;
                int col = tn + wc + n * 16 + fr;
                store_c(&C[(size_t)row * ldc + col], acc[m][n][r]);
            }
}

// ---------- trig table: trig[t][d] = cos, trig[t][512+d] = sin (fp16) ----------
__global__ __launch_bounds__(256)
void trig_table(u16* __restrict__ trig) {
    const int t = blockIdx.x;
    const float L = 0.025952563241307517f;  // log2(10000)/512
    u16* row = trig + (size_t)t * 1024;
#pragma unroll
    for (int i = 0; i < 2; ++i) {
        int d = threadIdx.x + i * 256;
        float invf = exp2f(-(float)d * L);
        float ang = (float)t * invf;
        float s, c;
        sincosf(ang, &s, &c);
        row[d] = f2h(c);
        row[512 + d] = f2h(s);
    }
}

// ---------- RoPE + L2 norm * sqk*32, in-place on Q,K ----------
__global__ __launch_bounds__(256)
void rope_norm(u16* __restrict__ qkv, const float* __restrict__ sqk,
               const u16* __restrict__ trig) {
    const int row = blockIdx.x;        // b*2048 + t
    const int t = row & 2047;
    u16* qp = qkv + (size_t)row * 3072;
    u16* kp = qp + 1024;
    const u16* tb = trig + (size_t)t * 1024;

    float q0v[2], q1v[2], k0v[2], k1v[2];
    float ssq_q = 0.f, ssq_k = 0.f;

#pragma unroll
    for (int i = 0; i < 2; ++i) {
        int d = threadIdx.x + i * 256;           // 0..511
        float c = h2f(tb[d]);
        float s = h2f(tb[512 + d]);
        float q0 = bf2f(qp[d]), q1 = bf2f(qp[d + 512]);
        float k0 = bf2f(kp[d]), k1 = bf2f(kp[d + 512]);
        float nq0 = q0 * c - q1 * s;
        float nq1 = q1 * c + q0 * s;
        float nk0 = k0 * c - k1 * s;
        float nk1 = k1 * c + k0 * s;
        q0v[i] = nq0; q1v[i] = nq1; k0v[i] = nk0; k1v[i] = nk1;
        ssq_q += nq0 * nq0 + nq1 * nq1;
        ssq_k += nk0 * nk0 + nk1 * nk1;
    }

#pragma unroll
    for (int off = 32; off; off >>= 1) {
        ssq_q += __shfl_xor(ssq_q, off);
        ssq_k += __shfl_xor(ssq_k, off);
    }
    __shared__ float red[8];
    int wave = threadIdx.x >> 6, lane = threadIdx.x & 63;
    if (lane == 0) { red[wave] = ssq_q; red[4 + wave] = ssq_k; }
    __syncthreads();
    float rq = rsqrtf(red[0] + red[1] + red[2] + red[3]);
    float rk = rsqrtf(red[4] + red[5] + red[6] + red[7]);

#pragma unroll
    for (int i = 0; i < 2; ++i) {
        int d = threadIdx.x + i * 256;
        float s0 = sqk[d] * 32.f, s1 = sqk[d + 512] * 32.f;
        qp[d]       = f2bf(q0v[i] * rq * s0);
        qp[d + 512] = f2bf(q1v[i] * rq * s1);
        kp[d]       = f2bf(k0v[i] * rk * s0);
        kp[d + 512] = f2bf(k1v[i] * rk * s1);
    }
}

// ---------- V transpose: VT[b][n][k] = qkv[(b*2048+k)][2048+n] ----------
__global__ __launch_bounds__(256)
void transpose_v(const u16* __restrict__ qkv, u16* __restrict__ VT) {
    __shared__ u16 tile[32][33];
    int b = blockIdx.z;
    int n0 = blockIdx.x * 32;
    int k0 = blockIdx.y * 32;
    int tx = threadIdx.x, ty = threadIdx.y;
    const u16* src = qkv + (size_t)b * 2048 * 3072 + 2048;
#pragma unroll
    for (int i = 0; i < 4; ++i)
        tile[ty + i * 8][tx] = src[(size_t)(k0 + ty + i * 8) * 3072 + n0 + tx];
    __syncthreads();
    u16* dst = VT + (size_t)b * 1024 * 2048;
#pragma unroll
    for (int i = 0; i < 4; ++i)
        dst[(size_t)(n0 + ty + i * 8) * 2048 + k0 + tx] = tile[tx][ty + i * 8];
}

// ---------- in-place causal softmax over fp16 S rows -> bf16 P (same bytes) ----------
// S slot: [2048 rows][2048 fp16]. Row r: valid cols [0, r]; P bf16 overwrites row.
__global__ __launch_bounds__(256)
void softmax_inplace(u16* __restrict__ Sbase) {
    const int r = blockIdx.x;
    const int b = blockIdx.y;
    u16* row = Sbase + (size_t)b * 4194304 + (size_t)r * 2048;
    const int n = r + 1;
    const int tid = threadIdx.x;

    union { uint4 u; u16 h[8]; } U;
    U.u = *reinterpret_cast<const uint4*>(row + tid * 8);
    float v[8];
    float m = -1e30f;
#pragma unroll
    for (int i = 0; i < 8; ++i) {
        int c = tid * 8 + i;
        v[i] = (c < n) ? h2f(U.h[i]) : -1e30f;
        m = fmaxf(m, v[i]);
    }
#pragma unroll
    for (int off = 32; off; off >>= 1) m = fmaxf(m, __shfl_xor(m, off));
    __shared__ float redm[4], redsum[4];
    int wave = tid >> 6, lane = tid & 63;
    if (lane == 0) redm[wave] = m;
    __syncthreads();
    m = fmaxf(fmaxf(redm[0], redm[1]), fmaxf(redm[2], redm[3]));
    float M = 32.f * m;

    float sum = 0.f;
#pragma unroll
    for (int i = 0; i < 8; ++i) {
        int c = tid * 8 + i;
        float e = (c < n) ? __expf(32.f * v[i] - M) : 0.f;
        v[i] = e;
        sum += e;
    }
#pragma unroll
    for (int off = 32; off; off >>= 1) sum += __shfl_xor(sum, off);
    if (lane == 0) redsum[wave] = sum;
    __syncthreads();   // also orders all row reads before writes
    sum = redsum[0] + redsum[1] + redsum[2] + redsum[3];
    float inv = 1.f / sum;

    union { uint4 u; u16 h[8]; } O;
#pragma unroll
    for (int i = 0; i < 8; ++i) O.h[i] = f2bf(v[i] * inv);
    *reinterpret_cast<uint4*>(row + tid * 8) = O.u;
}

// ---------- host launcher ----------
extern "C" void kernel_launch(void* const* d_in, const int* in_sizes, int n_in,
                              void* d_out, int out_size, void* d_ws, size_t ws_size,
                              hipStream_t stream) {
    const float* x   = (const float*)d_in[0];   // [4,2048,1024]
    const float* w   = (const float*)d_in[1];   // [3072,1024]
    const float* sqk = (const float*)d_in[2];   // [1024]
    float* out = (float*)d_out;

    const size_t SZ_XB  = (size_t)8192 * 1024 * 2;        // 16.8 MB, aliased by VT later
    const size_t SZ_WB  = (size_t)3072 * 1024 * 2;        //  6.3 MB
    const size_t SZ_QKV = (size_t)8192 * 3072 * 2;        // 50.3 MB
    const size_t SZ_S   = (size_t)4 * 2048 * 2048 * 2;    // 33.6 MB (fp16, 4 slots)
    const size_t SZ_TR  = (size_t)2048 * 1024 * 2;        //  4.2 MB
    if (ws_size < SZ_XB + SZ_WB + SZ_QKV + SZ_S + SZ_TR) return;

    char* ws = (char*)d_ws;
    u16* xb   = (u16*)ws;  ws += SZ_XB;
    u16* wb   = (u16*)ws;  ws += SZ_WB;
    u16* qkv  = (u16*)ws;  ws += SZ_QKV;
    u16* S    = (u16*)ws;  ws += SZ_S;
    u16* trig = (u16*)ws;
    u16* VT   = xb;   // alias: xb dead after QKV GEMM

    f32_to_bf16<<<2048, 256, 0, stream>>>(x, xb, 8192 * 1024);
    f32_to_bf16<<<768, 256, 0, stream>>>(w, wb, 3072 * 1024);

    // qkv = x @ W^T : [8192,3072]
    gemm_bt<0, u16><<<dim3(3072 / BN, 8192 / BM, 1), 256, 0, stream>>>(
        xb, wb, qkv, 1024, 1024, 1024, 3072, 0, 0, 0);

    trig_table<<<2048, 256, 0, stream>>>(trig);
    rope_norm<<<8192, 256, 0, stream>>>(qkv, sqk, trig);

    transpose_v<<<dim3(32, 64, 4), dim3(32, 8), 0, stream>>>(qkv, VT);

    // S = Q @ K^T, all 4 batches, causal tiles, fp16 output
    gemm_bt<1, _Float16><<<dim3(16, 16, 4), 256, 0, stream>>>(
        qkv, qkv + 1024, (_Float16*)S, 1024, 3072, 3072, 2048,
        (long)2048 * 3072, (long)2048 * 3072, (long)2048 * 2048);

    softmax_inplace<<<dim3(2048, 4), 256, 0, stream>>>(S);

    // out = P @ V, all 4 batches (P bf16 in S rows, lda=2048)
    gemm_bt<2, float><<<dim3(8, 16, 4), 256, 0, stream>>>(
        S, VT, out, 2048, 2048, 2048, 1024,
        (long)2048 * 2048, (long)1024 * 2048, (long)2048 * 1024);
}

// Round 4
// 168.194 us; speedup vs baseline: 2.5551x; 1.4238x over previous
//
#include <hip/hip_runtime.h>

typedef unsigned short u16;
typedef short s16x8 __attribute__((ext_vector_type(8)));
typedef float f32x4 __attribute__((ext_vector_type(4)));

// ---------- scalar dtype helpers ----------
__device__ __forceinline__ u16 f2bf(float f) {
    union { float f; unsigned u; } v; v.f = f;
    unsigned r = v.u + 0x7FFFu + ((v.u >> 16) & 1u);   // RNE
    return (u16)(r >> 16);
}
__device__ __forceinline__ float bf2f(u16 h) {
    union { unsigned u; float f; } v; v.u = ((unsigned)h) << 16;
    return v.f;
}
__device__ __forceinline__ u16 f2h(float f) {
    _Float16 h = (_Float16)f;
    union { _Float16 h; u16 u; } v; v.h = h; return v.u;
}
__device__ __forceinline__ float h2f(u16 u) {
    union { u16 u; _Float16 h; } v; v.u = u; return (float)v.h;
}

// async global->LDS, 16B per lane; LDS dest = wave-uniform base + lane*16
__device__ __forceinline__ void gl_lds16(const u16* g, u16* l) {
    __builtin_amdgcn_global_load_lds(
        (const __attribute__((address_space(1))) void*)g,
        (__attribute__((address_space(3))) void*)l,
        16, 0, 0);
}

// ---------- fp32 -> bf16 convert ----------
__global__ __launch_bounds__(256) void f32_to_bf16(const float* __restrict__ in,
                                                   u16* __restrict__ out, int n) {
    int i = (blockIdx.x * 256 + threadIdx.x) * 4;
    int stride = gridDim.x * 256 * 4;
    for (; i < n; i += stride) {
        float4 v = *reinterpret_cast<const float4*>(in + i);
        ushort4 o;
        o.x = f2bf(v.x); o.y = f2bf(v.y); o.z = f2bf(v.z); o.w = f2bf(v.w);
        *reinterpret_cast<ushort4*>(out + i) = o;
    }
}

template <typename CT>
__device__ __forceinline__ void store_c(CT* p, float v) {
    if constexpr (__is_same(CT, u16))            *p = f2bf(v);
    else if constexpr (__is_same(CT, _Float16))  *p = (_Float16)v;
    else                                         *p = v;
}

// swizzled LDS fragment read: base in u16, row in [0,128), kk in {0,1}, fq in [0,4)
__device__ __forceinline__ s16x8 ldfrag(const u16* base, int row, int kk, int fq) {
    int cb = ((kk << 6) + (fq << 4)) ^ ((row & 7) << 4);   // byte col, XOR bits 4-6
    return *reinterpret_cast<const s16x8*>(base + row * 64 + (cb >> 1));
}

// ---------- bf16 GEMM, C = A @ B^T ----------
// 128x128 tile, BK=64, double-buffered LDS (64KB), counted vmcnt, raw barriers,
// XOR-swizzled LDS (write via pre-swizzled global src, read via swizzled addr).
// MODE 0: plain. MODE 1: causal tile skip (grid x,y,z). MODE 2: PV with per-row-tile
// K limit, longest-first order, grid (N/128, 16*4, 1), y decodes (batch, rowtile).
template <int MODE, typename CT>
__global__ __launch_bounds__(256)
void gemm_bt(const u16* __restrict__ A, const u16* __restrict__ B, CT* __restrict__ C,
             int K, int lda, int ldb, int ldc, long sA, long sB, long sC) {
    int bx = blockIdx.x, by = blockIdx.y, bz = blockIdx.z;
    if (MODE == 1 && bx > by) return;
    if (MODE == 2) { bz = blockIdx.y & 3; by = 15 - (int)(blockIdx.y >> 2); }
    A += (size_t)bz * sA; B += (size_t)bz * sB; C += (size_t)bz * sC;
    int kend = K;
    if (MODE == 2) { int kl = (by + 1) * 128; kend = kl < K ? kl : K; }
    const int NT = kend >> 6;   // K-tiles of 64

    __shared__ u16 lds[32768];  // [2 bufs][ A 8192 u16 | B 8192 u16 ]

    const int tid  = threadIdx.x;
    const int lane = tid & 63;
    const int wave = tid >> 6;
    const int wr = (wave >> 1) * 64;
    const int wc = (wave & 1) * 64;
    const int fr = lane & 15;
    const int fq = lane >> 4;
    const int tm = by * 128, tn = bx * 128;

    // --- staging precompute (8 x 16B loads per thread per K-tile: 4 A + 4 B) ---
    // linear LDS dest o = j*4096 + tid*16 bytes  -> row = j*32 + tid/8, cb' = (tid&7)*16
    // source col pre-swizzled so LDS[row][cb'] = A[row][(cb' ^ ((row&7)<<4))/2]
    const int srow = tid >> 3;                                  // 0..31
    const int gco  = (((tid & 7) ^ (srow & 7)) << 3);           // u16 col after unswizzle
    const u16* aR[4]; const u16* bR[4];
#pragma unroll
    for (int j = 0; j < 4; ++j) {
        aR[j] = A + (size_t)(tm + j * 32 + srow) * lda + gco;
        bR[j] = B + (size_t)(tn + j * 32 + srow) * ldb + gco;
    }

#define STAGE(b2, k0) do {                                                  \
    _Pragma("unroll") for (int j = 0; j < 4; ++j)                           \
        gl_lds16(aR[j] + (k0), lds + (b2) * 16384 + j * 2048 + wave * 512); \
    _Pragma("unroll") for (int j = 0; j < 4; ++j)                           \
        gl_lds16(bR[j] + (k0), lds + (b2) * 16384 + 8192 + j * 2048 + wave * 512); \
  } while (0)

    f32x4 acc[4][4];
#pragma unroll
    for (int m = 0; m < 4; ++m)
#pragma unroll
        for (int n = 0; n < 4; ++n) acc[m][n] = {0.f, 0.f, 0.f, 0.f};

    STAGE(0, 0);
    if (NT > 1) STAGE(1, 64);

    for (int t = 0; t < NT; ++t) {
        const int buf = t & 1;
        // tile t's 8 loads are the oldest; tile t+1's 8 (if staged) may stay in flight
        if (t + 1 < NT) { asm volatile("s_waitcnt vmcnt(8)" ::: "memory"); }
        else            { asm volatile("s_waitcnt vmcnt(0)" ::: "memory"); }
        __builtin_amdgcn_s_barrier();
        __builtin_amdgcn_sched_barrier(0);

        const u16* Ab = lds + buf * 16384;
        const u16* Bb = Ab + 8192;
        s16x8 bf0[4], bf1[4];
#pragma unroll
        for (int n = 0; n < 4; ++n) {
            bf0[n] = ldfrag(Bb, wc + n * 16 + fr, 0, fq);
            bf1[n] = ldfrag(Bb, wc + n * 16 + fr, 1, fq);
        }
        __builtin_amdgcn_s_setprio(1);
#pragma unroll
        for (int m = 0; m < 4; ++m) {
            s16x8 a0 = ldfrag(Ab, wr + m * 16 + fr, 0, fq);
            s16x8 a1 = ldfrag(Ab, wr + m * 16 + fr, 1, fq);
#pragma unroll
            for (int n = 0; n < 4; ++n) {
                acc[m][n] = __builtin_amdgcn_mfma_f32_16x16x32_bf16(a0, bf0[n], acc[m][n], 0, 0, 0);
                acc[m][n] = __builtin_amdgcn_mfma_f32_16x16x32_bf16(a1, bf1[n], acc[m][n], 0, 0, 0);
            }
        }
        __builtin_amdgcn_s_setprio(0);
        __builtin_amdgcn_sched_barrier(0);
        __builtin_amdgcn_s_barrier();           // all waves done reading buf
        if (t + 2 < NT) STAGE(buf, (t + 2) << 6);
    }
#undef STAGE

    // epilogue: D row=(lane>>4)*4+r, col=lane&15 (m89-verified)
#pragma unroll
    for (int m = 0; m < 4; ++m)
#pragma unroll
        for (int n = 0; n < 4; ++n)
#pragma unroll
            for (int r = 0; r < 4; ++r) {
                int row = tm + wr + m * 16 + fq * 4 + r;
                int col = tn + wc + n * 16 + fr;
                store_c(&C[(size_t)row * ldc + col], acc[m][n][r]);
            }
}

// ---------- trig table: trig[t][d] = cos, trig[t][512+d] = sin (fp16) ----------
__global__ __launch_bounds__(256)
void trig_table(u16* __restrict__ trig) {
    const int t = blockIdx.x;
    const float L = 0.025952563241307517f;  // log2(10000)/512
    u16* row = trig + (size_t)t * 1024;
#pragma unroll
    for (int i = 0; i < 2; ++i) {
        int d = threadIdx.x + i * 256;
        float invf = exp2f(-(float)d * L);
        float ang = (float)t * invf;
        float s, c;
        sincosf(ang, &s, &c);
        row[d] = f2h(c);
        row[512 + d] = f2h(s);
    }
}

// ---------- RoPE + L2 norm * sqk*32, in-place on Q,K ----------
__global__ __launch_bounds__(256)
void rope_norm(u16* __restrict__ qkv, const float* __restrict__ sqk,
               const u16* __restrict__ trig) {
    const int row = blockIdx.x;        // b*2048 + t
    const int t = row & 2047;
    u16* qp = qkv + (size_t)row * 3072;
    u16* kp = qp + 1024;
    const u16* tb = trig + (size_t)t * 1024;

    float q0v[2], q1v[2], k0v[2], k1v[2];
    float ssq_q = 0.f, ssq_k = 0.f;

#pragma unroll
    for (int i = 0; i < 2; ++i) {
        int d = threadIdx.x + i * 256;           // 0..511
        float c = h2f(tb[d]);
        float s = h2f(tb[512 + d]);
        float q0 = bf2f(qp[d]), q1 = bf2f(qp[d + 512]);
        float k0 = bf2f(kp[d]), k1 = bf2f(kp[d + 512]);
        float nq0 = q0 * c - q1 * s;
        float nq1 = q1 * c + q0 * s;
        float nk0 = k0 * c - k1 * s;
        float nk1 = k1 * c + k0 * s;
        q0v[i] = nq0; q1v[i] = nq1; k0v[i] = nk0; k1v[i] = nk1;
        ssq_q += nq0 * nq0 + nq1 * nq1;
        ssq_k += nk0 * nk0 + nk1 * nk1;
    }

#pragma unroll
    for (int off = 32; off; off >>= 1) {
        ssq_q += __shfl_xor(ssq_q, off);
        ssq_k += __shfl_xor(ssq_k, off);
    }
    __shared__ float red[8];
    int wave = threadIdx.x >> 6, lane = threadIdx.x & 63;
    if (lane == 0) { red[wave] = ssq_q; red[4 + wave] = ssq_k; }
    __syncthreads();
    float rq = rsqrtf(red[0] + red[1] + red[2] + red[3]);
    float rk = rsqrtf(red[4] + red[5] + red[6] + red[7]);

#pragma unroll
    for (int i = 0; i < 2; ++i) {
        int d = threadIdx.x + i * 256;
        float s0 = sqk[d] * 32.f, s1 = sqk[d + 512] * 32.f;
        qp[d]       = f2bf(q0v[i] * rq * s0);
        qp[d + 512] = f2bf(q1v[i] * rq * s1);
        kp[d]       = f2bf(k0v[i] * rk * s0);
        kp[d + 512] = f2bf(k1v[i] * rk * s1);
    }
}

// ---------- V transpose: VT[b][n][k] = qkv[(b*2048+k)][2048+n] ----------
__global__ __launch_bounds__(256)
void transpose_v(const u16* __restrict__ qkv, u16* __restrict__ VT) {
    __shared__ u16 tile[32][33];
    int b = blockIdx.z;
    int n0 = blockIdx.x * 32;
    int k0 = blockIdx.y * 32;
    int tx = threadIdx.x, ty = threadIdx.y;
    const u16* src = qkv + (size_t)b * 2048 * 3072 + 2048;
#pragma unroll
    for (int i = 0; i < 4; ++i)
        tile[ty + i * 8][tx] = src[(size_t)(k0 + ty + i * 8) * 3072 + n0 + tx];
    __syncthreads();
    u16* dst = VT + (size_t)b * 1024 * 2048;
#pragma unroll
    for (int i = 0; i < 4; ++i)
        dst[(size_t)(n0 + ty + i * 8) * 2048 + k0 + tx] = tile[tx][ty + i * 8];
}

// ---------- in-place causal softmax over fp16 S rows -> bf16 P (same bytes) ----------
// Only cols [0, ((r>>7)+1)*128) are touched — exactly what PV reads.
__global__ __launch_bounds__(256)
void softmax_inplace(u16* __restrict__ Sbase) {
    const int r = blockIdx.x;
    const int b = blockIdx.y;
    u16* row = Sbase + (size_t)b * 4194304 + (size_t)r * 2048;
    const int n = r + 1;
    const int kcap = ((r >> 7) + 1) << 7;
    const int tid = threadIdx.x;
    const bool act = (tid * 8) < kcap;

    union { uint4 u; u16 h[8]; } U;
    if (act) U.u = *reinterpret_cast<const uint4*>(row + tid * 8);
    float v[8];
    float m = -1e30f;
#pragma unroll
    for (int i = 0; i < 8; ++i) {
        int c = tid * 8 + i;
        v[i] = (act && c < n) ? h2f(U.h[i]) : -1e30f;
        m = fmaxf(m, v[i]);
    }
#pragma unroll
    for (int off = 32; off; off >>= 1) m = fmaxf(m, __shfl_xor(m, off));
    __shared__ float redm[4], redsum[4];
    int wave = tid >> 6, lane = tid & 63;
    if (lane == 0) redm[wave] = m;
    __syncthreads();
    m = fmaxf(fmaxf(redm[0], redm[1]), fmaxf(redm[2], redm[3]));
    float M = 32.f * m;

    float sum = 0.f;
#pragma unroll
    for (int i = 0; i < 8; ++i) {
        int c = tid * 8 + i;
        float e = (v[i] > -1e29f) ? __expf(32.f * v[i] - M) : 0.f;
        if (c >= n) e = 0.f;
        v[i] = e;
        sum += e;
    }
#pragma unroll
    for (int off = 32; off; off >>= 1) sum += __shfl_xor(sum, off);
    if (lane == 0) redsum[wave] = sum;
    __syncthreads();
    sum = redsum[0] + redsum[1] + redsum[2] + redsum[3];
    float inv = 1.f / sum;

    if (act) {
        union { uint4 u; u16 h[8]; } O;
#pragma unroll
        for (int i = 0; i < 8; ++i) O.h[i] = f2bf(v[i] * inv);
        *reinterpret_cast<uint4*>(row + tid * 8) = O.u;
    }
}

// ---------- host launcher ----------
extern "C" void kernel_launch(void* const* d_in, const int* in_sizes, int n_in,
                              void* d_out, int out_size, void* d_ws, size_t ws_size,
                              hipStream_t stream) {
    const float* x   = (const float*)d_in[0];   // [4,2048,1024]
    const float* w   = (const float*)d_in[1];   // [3072,1024]
    const float* sqk = (const float*)d_in[2];   // [1024]
    float* out = (float*)d_out;

    const size_t SZ_XB  = (size_t)8192 * 1024 * 2;        // aliased by VT later
    const size_t SZ_WB  = (size_t)3072 * 1024 * 2;
    const size_t SZ_QKV = (size_t)8192 * 3072 * 2;
    const size_t SZ_S   = (size_t)4 * 2048 * 2048 * 2;    // fp16, 4 slots
    const size_t SZ_TR  = (size_t)2048 * 1024 * 2;
    if (ws_size < SZ_XB + SZ_WB + SZ_QKV + SZ_S + SZ_TR) return;

    char* ws = (char*)d_ws;
    u16* xb   = (u16*)ws;  ws += SZ_XB;
    u16* wb   = (u16*)ws;  ws += SZ_WB;
    u16* qkv  = (u16*)ws;  ws += SZ_QKV;
    u16* S    = (u16*)ws;  ws += SZ_S;
    u16* trig = (u16*)ws;
    u16* VT   = xb;   // alias: xb dead after QKV GEMM

    f32_to_bf16<<<2048, 256, 0, stream>>>(x, xb, 8192 * 1024);
    f32_to_bf16<<<768, 256, 0, stream>>>(w, wb, 3072 * 1024);

    // qkv = x @ W^T : [8192,3072], grid 24x64 = 1536 blocks (3 clean rounds @ 2/CU)
    gemm_bt<0, u16><<<dim3(24, 64, 1), 256, 0, stream>>>(
        xb, wb, qkv, 1024, 1024, 1024, 3072, 0, 0, 0);

    trig_table<<<2048, 256, 0, stream>>>(trig);
    rope_norm<<<8192, 256, 0, stream>>>(qkv, sqk, trig);

    transpose_v<<<dim3(32, 64, 4), dim3(32, 8), 0, stream>>>(qkv, VT);

    // S = Q @ K^T, all 4 batches, causal tiles, fp16 output
    gemm_bt<1, _Float16><<<dim3(16, 16, 4), 256, 0, stream>>>(
        qkv, qkv + 1024, (_Float16*)S, 1024, 3072, 3072, 2048,
        (long)2048 * 3072, (long)2048 * 3072, (long)2048 * 2048);

    softmax_inplace<<<dim3(2048, 4), 256, 0, stream>>>(S);

    // out = P @ V, longest-first over row tiles, grid (8, 64)
    gemm_bt<2, float><<<dim3(8, 64, 1), 256, 0, stream>>>(
        S, VT, out, 2048, 2048, 2048, 1024,
        (long)2048 * 2048, (long)1024 * 2048, (long)2048 * 1024);
}